// Round 5
// baseline (379.802 us; speedup 1.0000x reference)
//
#include <hip/hip_runtime.h>

#define DIM 256
#define ELL_W 32
#define TM 32   // fused-tile rows per block

typedef __attribute__((ext_vector_type(8))) short short8;
typedef __attribute__((ext_vector_type(8))) unsigned short u16x8;
typedef __attribute__((ext_vector_type(4))) float f32x4;

__device__ __forceinline__ unsigned short f32_to_bf16(float x) {
    unsigned int u = __float_as_uint(x);
    unsigned int r = u + 0x7FFFu + ((u >> 16) & 1u);
    return (unsigned short)(r >> 16);
}
__device__ __forceinline__ float bf16_to_f32(unsigned short h) {
    return __uint_as_float(((unsigned int)h) << 16);
}

// ---- fused prep: ELL fill (atomic cursor; cursor ends as degree) + W->bf16
// transpose + x0->bf16 cast. Independent work split by block range. ----
__global__ void fillprep_kernel(const int* __restrict__ src, const int* __restrict__ dst,
                                int E, int* __restrict__ cursor, int* __restrict__ ell,
                                const float* __restrict__ W, unsigned short* __restrict__ Wt,
                                const float* __restrict__ x0, unsigned short* __restrict__ x0b,
                                int n4, int nbE) {
    int b = blockIdx.x;
    if (b < nbE) {
        int e = b * 256 + threadIdx.x;
        if (e < E) {
            int d = dst[e];
            int pos = atomicAdd(&cursor[d], 1);
            if (pos < ELL_W) ell[d * ELL_W + pos] = src[e];   // clamp: mem safety
        }
    } else if (b < nbE + DIM) {
        int k = b - nbE, n = threadIdx.x;
        Wt[n * DIM + k] = f32_to_bf16(W[k * DIM + n]);
    } else {
        int i = (b - nbE - DIM) * 256 + threadIdx.x;
        if (i < n4) {
            float4 v = ((const float4*)x0)[i];
            ushort4 o;
            o.x = f32_to_bf16(v.x); o.y = f32_to_bf16(v.y);
            o.z = f32_to_bf16(v.z); o.w = f32_to_bf16(v.w);
            ((ushort4*)x0b)[i] = o;
        }
    }
}

// ================= fused layer v2: aggregate -> LDS -> MFMA GEMM =================
// Fixes r2's occupancy failure: TM=32 rows/block (grid 1563 ~ 6 blocks/CU resident,
// LDS 16 KB), __launch_bounds__(256,5), and HALF-WAVE-per-node gather (each of the
// 8 half-waves owns 4 nodes sequentially, 4 row-loads in flight per half -> chain
// ~5 rounds/wave vs r2's ~21). Traffic stays minimal (no h round-trip: -77 MB/layer
// vs the split pipeline). Phase 2 is the r2-verified barrier-free K-loop: A-frags
// from swizzled hs (chunk ^= row&7), B-frags straight from L2-hot Wt; exactly one
// __syncthreads in the kernel.
template <bool LAST>
__global__ __launch_bounds__(256, 5) void layer_kernel(
    const unsigned short* __restrict__ xh, const unsigned short* __restrict__ x0b,
    const unsigned short* __restrict__ Wt,
    const int* __restrict__ deg, const int* __restrict__ ell,
    float* __restrict__ out_f32, unsigned short* __restrict__ out_bf16, int N)
{
    __shared__ unsigned short hs[TM * 256];   // 16 KB

    const int t    = threadIdx.x;
    const int w    = t >> 6;
    const int lane = t & 63;
    const int half = lane >> 5;
    const int hw   = (w << 1) + half;        // half-wave id, 0..7
    const int cl   = lane & 31;              // 16B-chunk index within the row
    const int c    = cl * 8;                 // column base (shorts)
    const int m0   = blockIdx.x * TM;

    // ---------------- phase 1: each half-wave aggregates 4 rows ----------------
    #pragma unroll
    for (int i = 0; i < TM / 8; i++) {
        const int lrow = hw * (TM / 8) + i;
        const int node = m0 + lrow;
        unsigned short* dp = &hs[lrow * 256 + (cl ^ (lrow & 7)) * 8];
        if (node < N) {
            const int dg = deg[node];
            const int ec = min(dg, ELL_W);
            const int* __restrict__ lst = ell + node * ELL_W;
            const float dscale = 0.9f / (float)max(dg, 1);
            const u16x8 xv = *(const u16x8*)(x0b + (size_t)node * DIM + c);
            float a[8];
            #pragma unroll
            for (int j = 0; j < 8; j++) a[j] = 0.f;
            int e = 0;
            for (; e + 4 <= ec; e += 4) {          // 4 independent row-loads in flight
                int s0 = lst[e], s1 = lst[e + 1], s2 = lst[e + 2], s3 = lst[e + 3];
                u16x8 v0 = *(const u16x8*)(xh + (size_t)s0 * DIM + c);
                u16x8 v1 = *(const u16x8*)(xh + (size_t)s1 * DIM + c);
                u16x8 v2 = *(const u16x8*)(xh + (size_t)s2 * DIM + c);
                u16x8 v3 = *(const u16x8*)(xh + (size_t)s3 * DIM + c);
                #pragma unroll
                for (int j = 0; j < 8; j++)
                    a[j] += (bf16_to_f32(v0[j]) + bf16_to_f32(v1[j]))
                          + (bf16_to_f32(v2[j]) + bf16_to_f32(v3[j]));
            }
            if (e + 2 <= ec) {
                int s0 = lst[e], s1 = lst[e + 1];
                u16x8 v0 = *(const u16x8*)(xh + (size_t)s0 * DIM + c);
                u16x8 v1 = *(const u16x8*)(xh + (size_t)s1 * DIM + c);
                #pragma unroll
                for (int j = 0; j < 8; j++)
                    a[j] += bf16_to_f32(v0[j]) + bf16_to_f32(v1[j]);
                e += 2;
            }
            if (e < ec) {
                int s0 = lst[e];
                u16x8 v0 = *(const u16x8*)(xh + (size_t)s0 * DIM + c);
                #pragma unroll
                for (int j = 0; j < 8; j++) a[j] += bf16_to_f32(v0[j]);
            }
            u16x8 o;
            #pragma unroll
            for (int j = 0; j < 8; j++)
                o[j] = f32_to_bf16(0.1f * bf16_to_f32(xv[j]) + dscale * a[j]);
            *(u16x8*)dp = o;
        } else {
            u16x8 z;
            #pragma unroll
            for (int j = 0; j < 8; j++) z[j] = 0;
            *(u16x8*)dp = z;                   // zero pad rows: GEMM reads them
        }
    }
    __syncthreads();   // hs complete

    // ------------- phase 2: out = relu(hs @ W), barrier-free K-loop -------------
    const int lm = lane & 15, q = lane >> 4;
    f32x4 acc[TM / 16][4];
    #pragma unroll
    for (int mi = 0; mi < TM / 16; mi++)
        #pragma unroll
        for (int ni = 0; ni < 4; ni++)
            acc[mi][ni] = (f32x4){0.f, 0.f, 0.f, 0.f};

    #pragma unroll
    for (int ks = 0; ks < 8; ks++) {
        short8 a[TM / 16];
        #pragma unroll
        for (int mi = 0; mi < TM / 16; mi++) {
            int row = mi * 16 + lm;
            int ch = (ks * 4 + q) ^ (row & 7);
            a[mi] = *(const short8*)&hs[row * 256 + ch * 8];
        }
        #pragma unroll
        for (int ni = 0; ni < 4; ni++) {
            int brow = w * 64 + ni * 16 + lm;
            short8 b = *(const short8*)(Wt + (size_t)brow * DIM + ks * 32 + q * 8);
            #pragma unroll
            for (int mi = 0; mi < TM / 16; mi++)
                acc[mi][ni] = __builtin_amdgcn_mfma_f32_16x16x32_bf16(a[mi], b, acc[mi][ni], 0, 0, 0);
        }
    }

    #pragma unroll
    for (int mi = 0; mi < TM / 16; mi++) {
        const int rowb = m0 + mi * 16 + q * 4;
        #pragma unroll
        for (int ni = 0; ni < 4; ni++) {
            const int col = w * 64 + ni * 16 + lm;
            #pragma unroll
            for (int r = 0; r < 4; r++) {
                int row = rowb + r;
                if (row < N) {
                    float v = fmaxf(acc[mi][ni][r], 0.0f);
                    if (LAST) out_f32[(size_t)row * DIM + col] = v;
                    else      out_bf16[(size_t)row * DIM + col] = f32_to_bf16(v);
                }
            }
        }
    }
}

extern "C" void kernel_launch(void* const* d_in, const int* in_sizes, int n_in,
                              void* d_out, int out_size, void* d_ws, size_t ws_size,
                              hipStream_t stream) {
    const float* x0  = (const float*)d_in[0];
    const int*   ei  = (const int*)d_in[1];
    const float* W   = (const float*)d_in[2];
    float*       out = (float*)d_out;

    const int N = in_sizes[0] / DIM;
    const int E = in_sizes[1] / 2;
    const int N_pad = (N + 127) & ~127;
    const int* src = ei;
    const int* dst = ei + E;

    char* ws = (char*)d_ws;
    size_t off = 0;
    auto alloc = [&](size_t bytes) { char* p = ws + off; off += (bytes + 15) & ~size_t(15); return p; };
    unsigned short* act0    = (unsigned short*)alloc((size_t)N_pad * DIM * 2);
    unsigned short* act1    = (unsigned short*)alloc((size_t)N_pad * DIM * 2);
    unsigned short* x0b     = (unsigned short*)alloc((size_t)N_pad * DIM * 2);
    unsigned short* Wt      = (unsigned short*)alloc((size_t)DIM * DIM * 2);
    int*   cursor   = (int*)  alloc((size_t)N * 4);          // ends as in-degree
    int*   ell      = (int*)  alloc((size_t)N * ELL_W * 4);  // 6.4 MB slot table

    // ---- ELL build + W/x0 prep ----
    const int nbE = (E + 255) / 256;
    const int n4 = N * DIM / 4;
    hipMemsetAsync(cursor, 0, (size_t)N * 4, stream);
    fillprep_kernel<<<nbE + DIM + (n4 + 255) / 256, 256, 0, stream>>>(
        src, dst, E, cursor, ell, W, Wt, x0, x0b, n4, nbE);

    // ---- 5 fused GCN layers (gather src ping-pongs; residual always x0b) ----
    const int nbt = (N + TM - 1) / TM;
    const unsigned short* gsrc = x0b;
    unsigned short* gdst = act0;
    for (int layer = 0; layer < 5; layer++) {
        if (layer == 4)
            layer_kernel<true><<<nbt, 256, 0, stream>>>(gsrc, x0b, Wt, cursor, ell,
                                                        out, nullptr, N);
        else
            layer_kernel<false><<<nbt, 256, 0, stream>>>(gsrc, x0b, Wt, cursor, ell,
                                                         nullptr, gdst, N);
        gsrc = gdst;
        gdst = (gdst == act0) ? act1 : act0;
    }
}

// Round 7
// 378.083 us; speedup vs baseline: 1.0045x; 1.0045x over previous
//
#include <hip/hip_runtime.h>

#define DIM 256
#define ELL_W 32

typedef __attribute__((ext_vector_type(8))) short short8;
typedef __attribute__((ext_vector_type(8))) unsigned short u16x8;
typedef __attribute__((ext_vector_type(4))) float f32x4;

__device__ __forceinline__ unsigned short f32_to_bf16(float x) {
    unsigned int u = __float_as_uint(x);
    unsigned int r = u + 0x7FFFu + ((u >> 16) & 1u);
    return (unsigned short)(r >> 16);
}
__device__ __forceinline__ float bf16_to_f32(unsigned short h) {
    return __uint_as_float(((unsigned int)h) << 16);
}

__device__ __forceinline__ void load_lds16(const void* g, void* l) {
    __builtin_amdgcn_global_load_lds(
        (const __attribute__((address_space(1))) unsigned int*)g,
        (__attribute__((address_space(3))) unsigned int*)l, 16, 0, 0);
}

// ---- fused prep: ELL fill (atomic cursor; cursor ends as degree) + W->bf16
// transpose + x0->bf16 cast. Independent work split by block range. ----
__global__ void fillprep_kernel(const int* __restrict__ src, const int* __restrict__ dst,
                                int E, int* __restrict__ cursor, int* __restrict__ ell,
                                const float* __restrict__ W, unsigned short* __restrict__ Wt,
                                const float* __restrict__ x0, unsigned short* __restrict__ x0b,
                                int n4, int nbE) {
    int b = blockIdx.x;
    if (b < nbE) {
        int e = b * 256 + threadIdx.x;
        if (e < E) {
            int d = dst[e];
            int pos = atomicAdd(&cursor[d], 1);
            if (pos < ELL_W) ell[d * ELL_W + pos] = src[e];   // clamp: mem safety
        }
    } else if (b < nbE + DIM) {
        int k = b - nbE, n = threadIdx.x;
        Wt[n * DIM + k] = f32_to_bf16(W[k * DIM + n]);
    } else {
        int i = (b - nbE - DIM) * 256 + threadIdx.x;
        if (i < n4) {
            float4 v = ((const float4*)x0)[i];
            ushort4 o;
            o.x = f32_to_bf16(v.x); o.y = f32_to_bf16(v.y);
            o.z = f32_to_bf16(v.z); o.w = f32_to_bf16(v.w);
            ((ushort4*)x0b)[i] = o;
        }
    }
}

// ---------------- gather aggregation (r4-verified, ELL-indexed) ----------------
// one 64-lane wave per node; lane owns 8 columns; the two wave halves process two
// edges concurrently (2 x 512B segments per load instruction); __shfl_xor combines.
__global__ __launch_bounds__(256) void aggregate_kernel(
    const unsigned short* __restrict__ xh, const unsigned short* __restrict__ x0b,
    const int* __restrict__ deg, const int* __restrict__ ell,
    unsigned short* __restrict__ h, int N)
{
    int node = blockIdx.x * 4 + (threadIdx.x >> 6);
    if (node >= N) return;
    const int lane = threadIdx.x & 63;
    const int half = lane >> 5;
    const int c    = (lane & 31) * 8;   // 8-column base

    const int dg = deg[node];
    const int ec = min(dg, ELL_W);
    const int* __restrict__ lst = ell + node * ELL_W;

    // hoisted epilogue operands: latency hides under the gather loop
    const float dscale = 0.9f / (float)max(dg, 1);
    const u16x8 xv = *(const u16x8*)(x0b + (size_t)node * DIM + c);

    float a[8];
    #pragma unroll
    for (int j = 0; j < 8; j++) a[j] = 0.f;

    int e = 0;
    for (; e + 4 <= ec; e += 4) {             // 4 edges per iter (2 per half)
        int s0 = lst[e + half];
        int s1 = lst[e + 2 + half];
        u16x8 v0 = *(const u16x8*)(xh + (size_t)s0 * DIM + c);
        u16x8 v1 = *(const u16x8*)(xh + (size_t)s1 * DIM + c);
        #pragma unroll
        for (int j = 0; j < 8; j++) a[j] += bf16_to_f32(v0[j]) + bf16_to_f32(v1[j]);
    }
    if (e + 2 <= ec) {                        // 2-edge remainder
        int s0 = lst[e + half];
        u16x8 v0 = *(const u16x8*)(xh + (size_t)s0 * DIM + c);
        #pragma unroll
        for (int j = 0; j < 8; j++) a[j] += bf16_to_f32(v0[j]);
        e += 2;
    }
    if (e < ec && half == 0) {                // odd tail: lo half only
        int s0 = lst[e];
        u16x8 v0 = *(const u16x8*)(xh + (size_t)s0 * DIM + c);
        #pragma unroll
        for (int j = 0; j < 8; j++) a[j] += bf16_to_f32(v0[j]);
    }

    // combine halves (all lanes participate)
    #pragma unroll
    for (int j = 0; j < 8; j++) a[j] += __shfl_xor(a[j], 32);

    if (half == 0) {
        u16x8 o;
        #pragma unroll
        for (int j = 0; j < 8; j++)
            o[j] = f32_to_bf16(0.1f * bf16_to_f32(xv[j]) + dscale * a[j]);
        *(u16x8*)(h + (size_t)node * DIM + c) = o;
    }
}

// ---------------- GEMM v6: 64x256 per block, A-only LDS staging ----------------
// Fixes v5's fatal bug: block now computes EXACTLY the rows it stages (64 rows x
// 256 cols = 4 waves x acc[4][4] fragment tiles; v5 staged 128 rows but computed
// only 64). h is staged once total (grid = N_pad/64, each row in one block).
// B fragments straight from L2-pinned Wt (128 KB; r2/r5-verified pattern) -> no Bs,
// LDS = 3 x 4 KB triple buffer with counted vmcnt: stage batch = 1 load/thread;
// per iter wait vmcnt(1) = "retire everything older than the newest batch" (FIFO
// drains b-loads and older batches regardless of compiler MFMA sinking), vmcnt(0)
// only at the last K-step. Addressing/swizzle identical to the r4-verified path.
template <bool LAST>
__global__ __launch_bounds__(256) void gemm_kernel(
    const unsigned short* __restrict__ h, const unsigned short* __restrict__ Wt,
    float* __restrict__ out_f32, unsigned short* __restrict__ out_bf16, int N)
{
    __shared__ unsigned short As[3][64 * 32];  // 3 x 4 KB

    const int t    = threadIdx.x;
    const int w    = t >> 6;
    const int lane = t & 63;
    const int lm   = lane & 15;
    const int q    = lane >> 4;
    const int m0   = blockIdx.x * 64;

    const int sr = t >> 2;                           // staged row 0..63
    const int sg = ((t & 3) ^ ((t >> 3) & 3)) * 8;   // swizzled source col offset
    const int xr = (lm >> 1) & 3;                    // read-side swizzle term

    f32x4 acc[4][4];
    #pragma unroll
    for (int mi = 0; mi < 4; mi++)
        #pragma unroll
        for (int ni = 0; ni < 4; ni++)
            acc[mi][ni] = (f32x4){0.f, 0.f, 0.f, 0.f};

    // one staging batch = 1 load_lds16 per thread (64 rows x 32 cols = 4 KB)
    auto stage = [&](int kb, int buf) {
        load_lds16(h + (size_t)(m0 + sr) * DIM + kb + sg, &As[buf][t * 8]);
    };

    stage(0, 0);     // batch 0
    stage(32, 1);    // batch 1

    const unsigned short* Bb = Wt + (size_t)(w * 64 + lm) * DIM + q * 8;

    #pragma unroll
    for (int ks = 0; ks < 8; ks++) {
        const int p = ks % 3;
        // retire everything older than the newest in-flight batch: guarantees the
        // batch feeding As[p] is complete; newest (1 load) stays in flight.
        if (ks < 7) asm volatile("s_waitcnt vmcnt(1)" ::: "memory");
        else        asm volatile("s_waitcnt vmcnt(0)" ::: "memory");
        __builtin_amdgcn_s_barrier();

        short8 a[4];
        #pragma unroll
        for (int mi = 0; mi < 4; mi++) {
            int row = mi * 16 + lm;
            a[mi] = *(const short8*)&As[p][row * 32 + (q ^ xr) * 8];
        }

        short8 b[4];
        #pragma unroll
        for (int ni = 0; ni < 4; ni++)
            b[ni] = *(const short8*)(Bb + (size_t)ni * 16 * DIM + ks * 32);

        if (ks < 6) stage((ks + 2) * 32, (ks + 2) % 3);   // batch ks+2

        #pragma unroll
        for (int ni = 0; ni < 4; ni++)
            #pragma unroll
            for (int mi = 0; mi < 4; mi++)
                acc[mi][ni] = __builtin_amdgcn_mfma_f32_16x16x32_bf16(a[mi], b[ni], acc[mi][ni], 0, 0, 0);
    }

    #pragma unroll
    for (int mi = 0; mi < 4; mi++) {
        const int rowb = m0 + mi * 16 + q * 4;
        #pragma unroll
        for (int ni = 0; ni < 4; ni++) {
            const int col = w * 64 + ni * 16 + lm;
            #pragma unroll
            for (int r = 0; r < 4; r++) {
                int row = rowb + r;
                if (row < N) {
                    float v = fmaxf(acc[mi][ni][r], 0.0f);
                    if (LAST) out_f32[(size_t)row * DIM + col] = v;
                    else      out_bf16[(size_t)row * DIM + col] = f32_to_bf16(v);
                }
            }
        }
    }
}

extern "C" void kernel_launch(void* const* d_in, const int* in_sizes, int n_in,
                              void* d_out, int out_size, void* d_ws, size_t ws_size,
                              hipStream_t stream) {
    const float* x0  = (const float*)d_in[0];
    const int*   ei  = (const int*)d_in[1];
    const float* W   = (const float*)d_in[2];
    float*       out = (float*)d_out;

    const int N = in_sizes[0] / DIM;
    const int E = in_sizes[1] / 2;
    const int N_pad = (N + 127) & ~127;
    const int* src = ei;
    const int* dst = ei + E;

    char* ws = (char*)d_ws;
    size_t off = 0;
    auto alloc = [&](size_t bytes) { char* p = ws + off; off += (bytes + 15) & ~size_t(15); return p; };
    unsigned short* h       = (unsigned short*)alloc((size_t)N_pad * DIM * 2);
    unsigned short* act     = (unsigned short*)alloc((size_t)N_pad * DIM * 2);
    unsigned short* x0b     = (unsigned short*)alloc((size_t)N_pad * DIM * 2);
    unsigned short* Wt      = (unsigned short*)alloc((size_t)DIM * DIM * 2);
    int*   cursor   = (int*)  alloc((size_t)N * 4);          // ends as in-degree
    int*   ell      = (int*)  alloc((size_t)N * ELL_W * 4);  // 6.4 MB slot table

    // ---- ELL build + W/x0 prep ----
    const int nbE = (E + 255) / 256;
    const int n4 = N * DIM / 4;
    hipMemsetAsync(cursor, 0, (size_t)N * 4, stream);
    fillprep_kernel<<<nbE + DIM + (n4 + 255) / 256, 256, 0, stream>>>(
        src, dst, E, cursor, ell, W, Wt, x0, x0b, n4, nbE);

    // ---- 5 GCN layers (layer 0 gathers from x0b; then act) ----
    dim3 ggrid(N_pad / 64);
    for (int layer = 0; layer < 5; layer++) {
        const unsigned short* gsrc = (layer == 0) ? x0b : act;
        aggregate_kernel<<<(N + 3) / 4, 256, 0, stream>>>(gsrc, x0b, cursor, ell, h, N);
        if (layer == 4)
            gemm_kernel<true><<<ggrid, 256, 0, stream>>>(h, Wt, out, nullptr, N);
        else
            gemm_kernel<false><<<ggrid, 256, 0, stream>>>(h, Wt, nullptr, act, N);
    }
}

// Round 8
// 361.668 us; speedup vs baseline: 1.0501x; 1.0454x over previous
//
#include <hip/hip_runtime.h>

#define DIM 256
#define ELL_W 32

typedef __attribute__((ext_vector_type(8))) short short8;
typedef __attribute__((ext_vector_type(8))) unsigned short u16x8;
typedef __attribute__((ext_vector_type(4))) float f32x4;

__device__ __forceinline__ unsigned short f32_to_bf16(float x) {
    unsigned int u = __float_as_uint(x);
    unsigned int r = u + 0x7FFFu + ((u >> 16) & 1u);
    return (unsigned short)(r >> 16);
}
__device__ __forceinline__ float bf16_to_f32(unsigned short h) {
    return __uint_as_float(((unsigned int)h) << 16);
}

__device__ __forceinline__ void load_lds16(const void* g, void* l) {
    __builtin_amdgcn_global_load_lds(
        (const __attribute__((address_space(1))) unsigned int*)g,
        (__attribute__((address_space(3))) unsigned int*)l, 16, 0, 0);
}

// ---- fused prep: ELL fill (atomic cursor; cursor ends as degree) + W->bf16
// transpose + x0->bf16 cast. Independent work split by block range. ----
__global__ void fillprep_kernel(const int* __restrict__ src, const int* __restrict__ dst,
                                int E, int* __restrict__ cursor, int* __restrict__ ell,
                                const float* __restrict__ W, unsigned short* __restrict__ Wt,
                                const float* __restrict__ x0, unsigned short* __restrict__ x0b,
                                int n4, int nbE) {
    int b = blockIdx.x;
    if (b < nbE) {
        int e = b * 256 + threadIdx.x;
        if (e < E) {
            int d = dst[e];
            int pos = atomicAdd(&cursor[d], 1);
            if (pos < ELL_W) ell[d * ELL_W + pos] = src[e];   // clamp: mem safety
        }
    } else if (b < nbE + DIM) {
        int k = b - nbE, n = threadIdx.x;
        Wt[n * DIM + k] = f32_to_bf16(W[k * DIM + n]);
    } else {
        int i = (b - nbE - DIM) * 256 + threadIdx.x;
        if (i < n4) {
            float4 v = ((const float4*)x0)[i];
            ushort4 o;
            o.x = f32_to_bf16(v.x); o.y = f32_to_bf16(v.y);
            o.z = f32_to_bf16(v.z); o.w = f32_to_bf16(v.w);
            ((ushort4*)x0b)[i] = o;
        }
    }
}

// ---------------- gather aggregation (r4-verified, ELL-indexed) ----------------
// one 64-lane wave per node; lane owns 8 columns; the two wave halves process two
// edges concurrently (2 x 512B segments per load instruction); __shfl_xor combines.
__global__ __launch_bounds__(256) void aggregate_kernel(
    const unsigned short* __restrict__ xh, const unsigned short* __restrict__ x0b,
    const int* __restrict__ deg, const int* __restrict__ ell,
    unsigned short* __restrict__ h, int N)
{
    int node = blockIdx.x * 4 + (threadIdx.x >> 6);
    if (node >= N) return;
    const int lane = threadIdx.x & 63;
    const int half = lane >> 5;
    const int c    = (lane & 31) * 8;   // 8-column base

    const int dg = deg[node];
    const int ec = min(dg, ELL_W);
    const int* __restrict__ lst = ell + node * ELL_W;

    // hoisted epilogue operands: latency hides under the gather loop
    const float dscale = 0.9f / (float)max(dg, 1);
    const u16x8 xv = *(const u16x8*)(x0b + (size_t)node * DIM + c);

    float a[8];
    #pragma unroll
    for (int j = 0; j < 8; j++) a[j] = 0.f;

    int e = 0;
    for (; e + 4 <= ec; e += 4) {             // 4 edges per iter (2 per half)
        int s0 = lst[e + half];
        int s1 = lst[e + 2 + half];
        u16x8 v0 = *(const u16x8*)(xh + (size_t)s0 * DIM + c);
        u16x8 v1 = *(const u16x8*)(xh + (size_t)s1 * DIM + c);
        #pragma unroll
        for (int j = 0; j < 8; j++) a[j] += bf16_to_f32(v0[j]) + bf16_to_f32(v1[j]);
    }
    if (e + 2 <= ec) {                        // 2-edge remainder
        int s0 = lst[e + half];
        u16x8 v0 = *(const u16x8*)(xh + (size_t)s0 * DIM + c);
        #pragma unroll
        for (int j = 0; j < 8; j++) a[j] += bf16_to_f32(v0[j]);
        e += 2;
    }
    if (e < ec && half == 0) {                // odd tail: lo half only
        int s0 = lst[e];
        u16x8 v0 = *(const u16x8*)(xh + (size_t)s0 * DIM + c);
        #pragma unroll
        for (int j = 0; j < 8; j++) a[j] += bf16_to_f32(v0[j]);
    }

    // combine halves (all lanes participate)
    #pragma unroll
    for (int j = 0; j < 8; j++) a[j] += __shfl_xor(a[j], 32);

    if (half == 0) {
        u16x8 o;
        #pragma unroll
        for (int j = 0; j < 8; j++)
            o[j] = f32_to_bf16(0.1f * bf16_to_f32(xv[j]) + dscale * a[j]);
        *(u16x8*)(h + (size_t)node * DIM + c) = o;
    }
}

// ---------------- LDS-staged MFMA GEMM (r4-verified): out = relu(h @ W) ----------
// Triple-buffered A+B staging with COUNTED vmcnt (T4). Stage batch ks+2 each iter;
// per iter a single raw s_barrier preceded by s_waitcnt vmcnt(4): the oldest batch
// (4 loads/thread) is complete, the newest stays in flight across the barrier
// (never drain to 0 in the main loop). B prefetched 2 K-tiles ahead into LDS —
// r7 showed on-demand global B-loads inside the fenced loop expose raw L2 latency.
template <bool LAST>
__global__ __launch_bounds__(256) void gemm_kernel(
    const unsigned short* __restrict__ h, const unsigned short* __restrict__ Wt,
    float* __restrict__ out_f32, unsigned short* __restrict__ out_bf16, int N)
{
    __shared__ unsigned short As[3][128 * 32];  // 3 x 8 KB
    __shared__ unsigned short Bs[3][128 * 32];  // 3 x 8 KB

    const int t    = threadIdx.x;
    const int w    = t >> 6;
    const int lane = t & 63;
    const int lm   = lane & 15;
    const int q    = lane >> 4;
    const int wm   = w >> 1, wn = w & 1;
    const int m0   = blockIdx.x * 128;
    const int n0   = blockIdx.y * 128;

    const int sr = t >> 2;
    const int sg = ((t & 3) ^ ((t >> 3) & 3)) * 8;   // swizzled source col offset
    const int xr = (lm >> 1) & 3;                    // read-side swizzle term

    f32x4 acc[4][4];
    #pragma unroll
    for (int mi = 0; mi < 4; mi++)
        #pragma unroll
        for (int ni = 0; ni < 4; ni++)
            acc[mi][ni] = (f32x4){0.f, 0.f, 0.f, 0.f};

    // one staging batch = 4 load_lds16 per thread (A/B x 2 halves)
    auto stage = [&](int kb, int buf) {
        #pragma unroll
        for (int half = 0; half < 2; half++) {
            int r = half * 64 + sr;
            int ldso = (half * 256 + t) * 8;
            load_lds16(h  + (size_t)(m0 + r) * DIM + kb + sg, &As[buf][ldso]);
            load_lds16(Wt + (size_t)(n0 + r) * DIM + kb + sg, &Bs[buf][ldso]);
        }
    };

    stage(0, 0);     // batch 0
    stage(32, 1);    // batch 1

    #pragma unroll
    for (int ks = 0; ks < 8; ks++) {
        const int p = ks % 3;
        // oldest outstanding batch (the one feeding buf p) must be complete;
        // newest (4 loads/thread) may remain in flight across the barrier.
        if (ks < 7) asm volatile("s_waitcnt vmcnt(4)" ::: "memory");
        else        asm volatile("s_waitcnt vmcnt(0)" ::: "memory");
        __builtin_amdgcn_s_barrier();

        short8 a[4];
        #pragma unroll
        for (int mi = 0; mi < 4; mi++) {
            int row = wm * 64 + mi * 16 + lm;
            a[mi] = *(const short8*)&As[p][row * 32 + (q ^ xr) * 8];
        }

        if (ks < 6) stage((ks + 2) * 32, (ks + 2) % 3);   // batch ks+2

        #pragma unroll
        for (int ni = 0; ni < 4; ni++) {
            int row = wn * 64 + ni * 16 + lm;
            short8 b = *(const short8*)&Bs[p][row * 32 + (q ^ xr) * 8];
            #pragma unroll
            for (int mi = 0; mi < 4; mi++)
                acc[mi][ni] = __builtin_amdgcn_mfma_f32_16x16x32_bf16(a[mi], b, acc[mi][ni], 0, 0, 0);
        }
    }

    #pragma unroll
    for (int mi = 0; mi < 4; mi++) {
        const int rowb = m0 + wm * 64 + mi * 16 + q * 4;
        #pragma unroll
        for (int ni = 0; ni < 4; ni++) {
            const int col = n0 + wn * 64 + ni * 16 + lm;
            #pragma unroll
            for (int r = 0; r < 4; r++) {
                int row = rowb + r;
                if (row < N) {
                    float v = fmaxf(acc[mi][ni][r], 0.0f);
                    if (LAST) out_f32[(size_t)row * DIM + col] = v;
                    else      out_bf16[(size_t)row * DIM + col] = f32_to_bf16(v);
                }
            }
        }
    }
}

extern "C" void kernel_launch(void* const* d_in, const int* in_sizes, int n_in,
                              void* d_out, int out_size, void* d_ws, size_t ws_size,
                              hipStream_t stream) {
    const float* x0  = (const float*)d_in[0];
    const int*   ei  = (const int*)d_in[1];
    const float* W   = (const float*)d_in[2];
    float*       out = (float*)d_out;

    const int N = in_sizes[0] / DIM;
    const int E = in_sizes[1] / 2;
    const int N_pad = (N + 127) & ~127;
    const int* src = ei;
    const int* dst = ei + E;

    char* ws = (char*)d_ws;
    size_t off = 0;
    auto alloc = [&](size_t bytes) { char* p = ws + off; off += (bytes + 15) & ~size_t(15); return p; };
    unsigned short* h       = (unsigned short*)alloc((size_t)N_pad * DIM * 2);
    unsigned short* act     = (unsigned short*)alloc((size_t)N_pad * DIM * 2);
    unsigned short* x0b     = (unsigned short*)alloc((size_t)N_pad * DIM * 2);
    unsigned short* Wt      = (unsigned short*)alloc((size_t)DIM * DIM * 2);
    int*   cursor   = (int*)  alloc((size_t)N * 4);          // ends as in-degree
    int*   ell      = (int*)  alloc((size_t)N * ELL_W * 4);  // 6.4 MB slot table

    // ---- ELL build + W/x0 prep ----
    const int nbE = (E + 255) / 256;
    const int n4 = N * DIM / 4;
    hipMemsetAsync(cursor, 0, (size_t)N * 4, stream);
    fillprep_kernel<<<nbE + DIM + (n4 + 255) / 256, 256, 0, stream>>>(
        src, dst, E, cursor, ell, W, Wt, x0, x0b, n4, nbE);

    // ---- 5 GCN layers (layer 0 gathers from x0b; then act) ----
    dim3 ggrid(N_pad / 128, 2);
    for (int layer = 0; layer < 5; layer++) {
        const unsigned short* gsrc = (layer == 0) ? x0b : act;
        aggregate_kernel<<<(N + 3) / 4, 256, 0, stream>>>(gsrc, x0b, cursor, ell, h, N);
        if (layer == 4)
            gemm_kernel<true><<<ggrid, 256, 0, stream>>>(h, Wt, out, nullptr, N);
        else
            gemm_kernel<false><<<ggrid, 256, 0, stream>>>(h, Wt, nullptr, act, N);
    }
}